// Round 2
// baseline (103.576 us; speedup 1.0000x reference)
//
#include <hip/hip_runtime.h>

#define NFULL 8192
#define BATCH 4
#define TT 256                       // square tile side
#define NT (NFULL / TT)              // 32 tiles per dim
#define JOBS_PER_B (NT * (NT + 1) / 2)   // 528 triangular tile pairs
#define TOTAL_JOBS (BATCH * JOBS_PER_B)  // 2112
#define IR 4                         // i-points per lane (64 lanes * 4 = 256 = TT)
#define LAMBDA 0.001

// ---- derived per-point values -------------------------------------------
__device__ __forceinline__ void load_point(const float* __restrict__ coords,
                                           const float* __restrict__ inputs,
                                           int b, int n,
                                           float& x, float& y, float& z,
                                           float& sq, float& w) {
    const float* cp = coords + (size_t)(b * NFULL + n) * 3;
    x = cp[0]; y = cp[1]; z = cp[2];
    sq = fmaf(x, x, fmaf(y, y, z * z));
    // softmax over C=2, channel 1  ==  sigmoid(a1 - a0)
    float a0 = inputs[(size_t)b * 2 * NFULL + n];
    float a1 = inputs[(size_t)b * 2 * NFULL + NFULL + n];
    w = 1.0f / (1.0f + __expf(a0 - a1));
}

__global__ void KUNi_zero_ws(double* ws) { ws[0] = 0.0; }

__global__ void KUNi_finalize(const double* __restrict__ ws, float* __restrict__ out) {
    const double scale = LAMBDA / ((double)BATCH * (double)NFULL * (double)NFULL);
    out[0] = (float)(ws[0] * scale);
}

__global__ __launch_bounds__(64)
void KUNi_dpp_kernel(const float* __restrict__ inputs,
                     const float* __restrict__ coords,
                     double* __restrict__ acc_out) {
    __shared__ float sX[TT], sY[TT], sZ[TT], sSQ[TT], sW[TT];

    const int tid = threadIdx.x;           // 0..63, one wave
    int bid = blockIdx.x;                  // 0..2111
    const int b = bid / JOBS_PER_B;
    int p = bid - b * JOBS_PER_B;

    // decode triangular (ti <= tj): row-major over rows of shrinking length
    int ti = 0;
    while (p >= NT - ti) { p -= NT - ti; ++ti; }
    const int tj = ti + p;

    // ---- stage j-tile into LDS (pre-scaled by -2 for the fma form) ------
    for (int jl = tid; jl < TT; jl += 64) {
        float x, y, z, sq, w;
        load_point(coords, inputs, b, tj * TT + jl, x, y, z, sq, w);
        sX[jl] = -2.0f * x;
        sY[jl] = -2.0f * y;
        sZ[jl] = -2.0f * z;
        sSQ[jl] = sq;
        sW[jl]  = w;
    }

    // ---- each lane owns IR i-points in registers ------------------------
    float ix[IR], iy[IR], iz[IR], isq[IR], iw[IR], acc[IR];
#pragma unroll
    for (int k = 0; k < IR; ++k) {
        load_point(coords, inputs, b, ti * TT + tid + k * 64,
                   ix[k], iy[k], iz[k], isq[k], iw[k]);
        acc[k] = 0.0f;
    }

    __syncthreads();

    // ---- main loop: 256 j's (wave-uniform broadcast) x IR i's per lane --
#pragma unroll 2
    for (int jj = 0; jj < TT; ++jj) {
        const float jx = sX[jj];
        const float jy = sY[jj];
        const float jz = sZ[jj];
        const float jsq = sSQ[jj];
        const float jw = sW[jj];
#pragma unroll
        for (int k = 0; k < IR; ++k) {
            float t = isq[k] + jsq;
            t = fmaf(jx, ix[k], t);
            t = fmaf(jy, iy[k], t);
            t = fmaf(jz, iz[k], t);
            t = fmaxf(t, 0.0f);
            float s = __builtin_amdgcn_sqrtf(t);   // v_sqrt_f32, no fixup
            acc[k] = fmaf(s, jw, acc[k]);          // fold w_j here, w_i later
        }
    }

    // ---- fold w_i, weight off-diagonal tiles by 2 (symmetry) ------------
    float v = 0.0f;
#pragma unroll
    for (int k = 0; k < IR; ++k) v = fmaf(iw[k], acc[k], v);
    if (ti != tj) v *= 2.0f;

    // ---- wave butterfly reduce, one f64 atomic per block ----------------
#pragma unroll
    for (int off = 32; off > 0; off >>= 1) v += __shfl_xor(v, off, 64);
    if (tid == 0) atomicAdd(acc_out, (double)v);
}

extern "C" void kernel_launch(void* const* d_in, const int* in_sizes, int n_in,
                              void* d_out, int out_size, void* d_ws, size_t ws_size,
                              hipStream_t stream) {
    const float* inputs = (const float*)d_in[0];   // (4, 2, 8192) f32
    const float* coords = (const float*)d_in[1];   // (4, 8192, 3) f32
    float* out = (float*)d_out;                    // scalar f32
    double* acc = (double*)d_ws;                   // 8-byte accumulator

    KUNi_zero_ws<<<1, 1, 0, stream>>>(acc);
    KUNi_dpp_kernel<<<TOTAL_JOBS, 64, 0, stream>>>(inputs, coords, acc);
    KUNi_finalize<<<1, 1, 0, stream>>>(acc, out);
}

// Round 3
// 88.135 us; speedup vs baseline: 1.1752x; 1.1752x over previous
//
#include <hip/hip_runtime.h>

#define NFULL 8192
#define BATCH 4
#define TT 256                       // square tile side
#define NT (NFULL / TT)              // 32 tiles per dim
#define JOBS_PER_B (NT * (NT + 1) / 2)   // 528 triangular tile pairs
#define TOTAL_JOBS (BATCH * JOBS_PER_B)  // 2112
#define IR 4                         // i-points per lane (64 lanes * 4 = 256 = TT)
#define JW 64                        // j-points per wave (4 waves * 64 = TT)
#define LAMBDA 0.001

struct alignas(16) F4 { float x, y, z, sq; };

// ---- derived per-point values -------------------------------------------
__device__ __forceinline__ void load_point(const float* __restrict__ coords,
                                           const float* __restrict__ inputs,
                                           int b, int n,
                                           float& x, float& y, float& z,
                                           float& sq, float& w) {
    const float* cp = coords + (size_t)(b * NFULL + n) * 3;
    x = cp[0]; y = cp[1]; z = cp[2];
    sq = fmaf(x, x, fmaf(y, y, z * z));
    // softmax over C=2, channel 1  ==  sigmoid(a1 - a0)
    float a0 = inputs[(size_t)b * 2 * NFULL + n];
    float a1 = inputs[(size_t)b * 2 * NFULL + NFULL + n];
    w = 1.0f / (1.0f + __expf(a0 - a1));
}

__global__ void KUNi_finalize(const float* __restrict__ partials,
                              float* __restrict__ out) {
    const int tid = threadIdx.x;          // 256
    const int lane = tid & 63, wv = tid >> 6;
    double s = 0.0;
    for (int i = tid; i < TOTAL_JOBS; i += 256) s += (double)partials[i];
#pragma unroll
    for (int off = 32; off > 0; off >>= 1) s += __shfl_xor(s, off, 64);
    __shared__ double sd[4];
    if (lane == 0) sd[wv] = s;
    __syncthreads();
    if (tid == 0) {
        const double scale = LAMBDA / ((double)BATCH * (double)NFULL * (double)NFULL);
        out[0] = (float)((sd[0] + sd[1] + sd[2] + sd[3]) * scale);
    }
}

__global__ __launch_bounds__(256)
void KUNi_dpp_kernel(const float* __restrict__ inputs,
                     const float* __restrict__ coords,
                     float* __restrict__ partials) {
    __shared__ F4 sj[TT];
    __shared__ float sw[TT];
    __shared__ float sred[4];

    const int tid = threadIdx.x;           // 0..255
    const int lane = tid & 63;
    const int wv = tid >> 6;               // wave 0..3
    int bid = blockIdx.x;                  // 0..2111
    const int b = bid / JOBS_PER_B;
    int p = bid - b * JOBS_PER_B;

    // decode triangular (ti <= tj): row-major over rows of shrinking length
    int ti = 0;
    while (p >= NT - ti) { p -= NT - ti; ++ti; }
    const int tj = ti + p;

    // ---- stage j-tile into LDS (pre-scaled by -2 for the fma form) ------
    {
        float x, y, z, sq, w;
        load_point(coords, inputs, b, tj * TT + tid, x, y, z, sq, w);
        sj[tid].x = -2.0f * x;
        sj[tid].y = -2.0f * y;
        sj[tid].z = -2.0f * z;
        sj[tid].sq = sq;
        sw[tid] = w;
    }

    // ---- each lane owns IR i-points in registers (same set every wave) --
    float ix[IR], iy[IR], iz[IR], isq[IR], iw[IR], acc[IR];
#pragma unroll
    for (int k = 0; k < IR; ++k) {
        load_point(coords, inputs, b, ti * TT + lane + k * 64,
                   ix[k], iy[k], iz[k], isq[k], iw[k]);
        acc[k] = 0.0f;
    }

    __syncthreads();

    // ---- each wave: its own 64-j chunk against all 256 i's --------------
    const int j0 = wv * JW;
#pragma unroll 4
    for (int jj = j0; jj < j0 + JW; ++jj) {
        const F4 jv = sj[jj];              // ds_read_b128, uniform broadcast
        const float jw = sw[jj];
#pragma unroll
        for (int k = 0; k < IR; ++k) {
            float t = isq[k] + jv.sq;
            t = fmaf(jv.x, ix[k], t);
            t = fmaf(jv.y, iy[k], t);
            t = fmaf(jv.z, iz[k], t);
            t = fmaxf(t, 0.0f);
            float s = __builtin_amdgcn_sqrtf(t);   // v_sqrt_f32, no fixup
            acc[k] = fmaf(s, jw, acc[k]);          // fold w_j here, w_i later
        }
    }

    // ---- fold w_i, weight off-diagonal tiles by 2 (symmetry) ------------
    float v = 0.0f;
#pragma unroll
    for (int k = 0; k < IR; ++k) v = fmaf(iw[k], acc[k], v);
    if (ti != tj) v *= 2.0f;

    // ---- wave butterfly, cross-wave via LDS, one store per block --------
#pragma unroll
    for (int off = 32; off > 0; off >>= 1) v += __shfl_xor(v, off, 64);
    if (lane == 0) sred[wv] = v;
    __syncthreads();
    if (tid == 0) partials[bid] = sred[0] + sred[1] + sred[2] + sred[3];
}

extern "C" void kernel_launch(void* const* d_in, const int* in_sizes, int n_in,
                              void* d_out, int out_size, void* d_ws, size_t ws_size,
                              hipStream_t stream) {
    const float* inputs = (const float*)d_in[0];   // (4, 2, 8192) f32
    const float* coords = (const float*)d_in[1];   // (4, 8192, 3) f32
    float* out = (float*)d_out;                    // scalar f32
    float* partials = (float*)d_ws;                // TOTAL_JOBS floats

    KUNi_dpp_kernel<<<TOTAL_JOBS, 256, 0, stream>>>(inputs, coords, partials);
    KUNi_finalize<<<1, 256, 0, stream>>>(partials, out);
}